// Round 2
// baseline (371.371 us; speedup 1.0000x reference)
//
#include <hip/hip_runtime.h>
#include <math.h>

// OFPenalty: power-iteration eigen-penalty on AAT = W W^T per batch, never
// materializing AAT. Round 4: fix the HBM access pattern.
//  - Diagnosis: column-slice reads of A are 64B-contiguous / 3136B-strided ->
//    ~2 TB/s regardless of pipelining (line over-fetch + poor DRAM locality).
//  - Fix: one-time repack A -> T[b][ch][c][16] (LDS-staged transpose, both
//    sides coalesced). Each k_step block then reads a SEQUENTIAL 224 KB run
//    (7 chunks x 32 KB), and T (103 MB) is L3-resident for steps 2..6.
//  - k_step keeps the double-buffered global_load_lds + counted vmcnt(8)
//    pipeline; per-wave register-usd removes one barrier/chunk; v-phase uses
//    staggered float4 LDS reads (bank-even).
//  - Runtime ws_size check: if workspace < 105 MB, fall back to the strided
//    (round-3) addressing on A directly.
// A: (64, 512, 28, 28) fp32 -> W: (64, 512, 784). x0: (64, 512, 1).

#define BB 64
#define CC 512
#define DD 784
#define DCH 16
#define NSPLIT 7
#define NCHPS 7         // chunks per split; NSPLIT*NCHPS = 49 = DD/DCH
#define F4PR 196        // float4 per row of A (784/4)
#define CHF4 2048       // float4 per chunk tile (512*16/4)
#define BF4 100352      // float4 per batch matrix (512*784/4)
#define FEPS 1e-12f

__device__ __forceinline__ void gload16(const float4* gp, float4* lp) {
    __builtin_amdgcn_global_load_lds(
        (const __attribute__((address_space(1))) void*)gp,
        (__attribute__((address_space(3))) void*)lp, 16, 0, 0);
}

__device__ __forceinline__ float blk_reduce(float s, float* red) {
    for (int off = 32; off; off >>= 1) s += __shfl_down(s, off, 64);
    int w = threadIdx.x >> 6;
    if ((threadIdx.x & 63) == 0) red[w] = s;
    __syncthreads();
    float t = red[0] + red[1] + red[2] + red[3];
    __syncthreads();                       // allow red[] reuse by caller
    return t;
}

// Repack A[b][c][d] -> T[b][ch][c][dd], ch = d>>4, dd = d&15.
// Per wave: 4 rows. Read 784 f4 sequential (global_load_lds -> LDS linear),
// then scatter-write 49 chunk-subtiles; each wave-store covers 4 x 256 B
// contiguous global segments. No cross-wave sync needed.
__global__ __launch_bounds__(256, 3)
void k_repack(const float* __restrict__ A, float* __restrict__ T) {
    __shared__ float4 st4[4 * 784];        // 4 waves x (4 rows x 196 f4) = 50 KB
    const int tid = threadIdx.x, lane = tid & 63, w = tid >> 6;
    const int b = blockIdx.y, slab = blockIdx.x;
    const int R = slab * 16 + w * 4;       // first row of this wave
    const float4* src = (const float4*)A + ((size_t)b * CC + R) * F4PR;
    float4* stw = st4 + w * 784;
#pragma unroll
    for (int i = 0; i < 12; i++)
        gload16(src + i * 64 + lane, stw + i * 64);
    if (lane < 16) gload16(src + 768 + lane, stw + 768);
    __builtin_amdgcn_sched_barrier(0);
    asm volatile("s_waitcnt vmcnt(0)" ::: "memory");
    __builtin_amdgcn_sched_barrier(0);
    float4* dst = (float4*)T + (size_t)b * BF4;
#pragma unroll
    for (int i = 0; i < 13; i++) {
        int m = i * 64 + lane;
        if (m < 784) {
            int ch = m >> 4, rem = m & 15, r = rem >> 2, dq = rem & 3;
            dst[(size_t)ch * CHF4 + (size_t)(R + r) * 4 + dq] =
                stw[r * 196 + ch * 4 + dq];
        }
    }
}

// vout[b][s][c] = partial of (AAT_b * normalize(sum_p xin[b][p][:]))_c over
// chunks ch = s*7 .. s*7+6. RP: read repacked T (sequential); else A (strided).
template <bool RP>
__global__ __launch_bounds__(256, 2)
void k_step(const float* __restrict__ M, const float* __restrict__ xin,
            const int nparts, float* __restrict__ vout) {
    __shared__ float4 tile4[2][CHF4];      // 2 x 32 KB
    __shared__ float  xs[CC];
    __shared__ float  uw[4][16];
    __shared__ float4 usdw4[4][4];         // per-wave copy of u_d
    __shared__ float  red[4];

    const int tid = threadIdx.x;
    const int b = blockIdx.y, s = blockIdx.x;
    const int lane = tid & 63, w = tid >> 6;
    const int rr = tid >> 2, widx = tid & 3;
    const float4* Mb = (const float4*)M + (size_t)b * BF4;

    auto issue = [&](int ch, int bufi) {
        float4* lb = &tile4[bufi][w * 64];
        if (RP) {
            const float4* g = Mb + (size_t)ch * CHF4 + tid;
#pragma unroll
            for (int i = 0; i < 8; i++) gload16(g + i * 256, lb + i * 256);
        } else {
            const float4* g = Mb + (size_t)rr * F4PR + ch * 4 + widx;
#pragma unroll
            for (int i = 0; i < 8; i++)
                gload16(g + (size_t)i * 64 * F4PR, lb + i * 256);
        }
    };

    issue(s * NCHPS, 0);                   // prologue: chunk 0, async

    // ---- phase A: normalize input (sum nparts partial segments)
    const float* xp = xin + (size_t)b * nparts * CC;
    float xv0 = 0.f, xv1 = 0.f;
    for (int p = 0; p < nparts; p++) {
        xv0 += xp[p * CC + tid];
        xv1 += xp[p * CC + tid + 256];
    }
    float ss = blk_reduce(xv0 * xv0 + xv1 * xv1, red);
    float rn = 1.0f / fmaxf(sqrtf(ss), FEPS);
    xs[tid] = xv0 * rn;
    xs[tid + 256] = xv1 * rn;              // visibility via bar1 (lgkm+barrier)

    float v0 = 0.f, v1 = 0.f;
    const int c0 = tid, c1 = tid + 256;
    const int stag = (lane >> 1) & 3;

    for (int j = 0; j < NCHPS; j++) {
        const int buf = j & 1;
        if (j < NCHPS - 1) {
            issue(s * NCHPS + j + 1, buf ^ 1);
            __builtin_amdgcn_sched_barrier(0);
            asm volatile("s_waitcnt vmcnt(8)" ::: "memory");  // current chunk done
        } else {
            __builtin_amdgcn_sched_barrier(0);
            asm volatile("s_waitcnt vmcnt(0)" ::: "memory");
        }
        asm volatile("s_waitcnt lgkmcnt(0)" ::: "memory");
        __builtin_amdgcn_s_barrier();                         // bar1: tile ready
        __builtin_amdgcn_sched_barrier(0);

        // ---- u-phase: u_d = <col d, x_hat>, linear b128 reads
        float4 ua = make_float4(0.f, 0.f, 0.f, 0.f);
        const float4* tp = tile4[buf];
#pragma unroll
        for (int i = 0; i < 8; i++) {
            float4 a4 = tp[tid + i * 256];
            float x = xs[rr + i * 64];
            ua.x += a4.x * x; ua.y += a4.y * x;
            ua.z += a4.z * x; ua.w += a4.w * x;
        }
#pragma unroll
        for (int off = 4; off <= 32; off <<= 1) {
            ua.x += __shfl_xor(ua.x, off, 64);
            ua.y += __shfl_xor(ua.y, off, 64);
            ua.z += __shfl_xor(ua.z, off, 64);
            ua.w += __shfl_xor(ua.w, off, 64);
        }
        if (lane < 4) {
            uw[w][lane * 4 + 0] = ua.x; uw[w][lane * 4 + 1] = ua.y;
            uw[w][lane * 4 + 2] = ua.z; uw[w][lane * 4 + 3] = ua.w;
        }
        __builtin_amdgcn_sched_barrier(0);
        asm volatile("s_waitcnt lgkmcnt(0)" ::: "memory");
        __builtin_amdgcn_s_barrier();                         // bar2: uw visible
        __builtin_amdgcn_sched_barrier(0);

        // per-wave usd copy: lanes 0..15 sum the 4 wave partials (same-wave
        // visibility -> lgkmcnt only, no barrier)
        if (lane < 16)
            ((float*)usdw4[w])[lane] =
                uw[0][lane] + uw[1][lane] + uw[2][lane] + uw[3][lane];
        asm volatile("s_waitcnt lgkmcnt(0)" ::: "memory");
        __builtin_amdgcn_sched_barrier(0);

        // ---- v-phase: v_c += tile[c][:] . u  (float4, q staggered -> bank-even)
        const float4* up = usdw4[w];
#pragma unroll
        for (int qq = 0; qq < 4; qq++) {
            int q = (qq + stag) & 3;
            float4 u = up[q];
            float4 a = tp[c0 * 4 + q];
            float4 bq = tp[c1 * 4 + q];
            v0 += a.x * u.x + a.y * u.y + a.z * u.z + a.w * u.w;
            v1 += bq.x * u.x + bq.y * u.y + bq.z * u.z + bq.w * u.w;
        }
        __builtin_amdgcn_sched_barrier(0);
        asm volatile("s_waitcnt lgkmcnt(0)" ::: "memory");
        __builtin_amdgcn_s_barrier();       // bar3: tile[buf] free for prefetch
        __builtin_amdgcn_sched_barrier(0);
    }

    float* vp = vout + ((size_t)b * NSPLIT + s) * CC;
    vp[c0] = v0;
    vp[c1] = v1;
}

// largest_b = <t5, x1>/<x1,x1>, x1 = t4/||t4||;  y = t5 - largest*x1
// t4, t5 are 7-way partial buffers [b][7][512].
__global__ void k_mid(const float* __restrict__ t4, const float* __restrict__ t5,
                      float* __restrict__ acc, float* __restrict__ y) {
    __shared__ float red[4];
    int b = blockIdx.x;
    const float* p4 = t4 + (size_t)b * NSPLIT * CC;
    const float* p5 = t5 + (size_t)b * NSPLIT * CC;
    float a0 = 0.f, a1 = 0.f, b0 = 0.f, b1 = 0.f;
    for (int p = 0; p < NSPLIT; p++) {
        a0 += p4[p * CC + threadIdx.x]; a1 += p4[p * CC + threadIdx.x + 256];
        b0 += p5[p * CC + threadIdx.x]; b1 += p5[p * CC + threadIdx.x + 256];
    }
    float ss4 = blk_reduce(a0 * a0 + a1 * a1, red);
    float rn = 1.0f / fmaxf(sqrtf(ss4), FEPS);
    float x10 = a0 * rn, x11 = a1 * rn;
    float num = blk_reduce(b0 * x10 + b1 * x11, red);
    float den = blk_reduce(x10 * x10 + x11 * x11, red);
    float largest = num / den;
    float* yp = y + (size_t)b * CC;
    yp[threadIdx.x] = b0 - largest * x10;
    yp[threadIdx.x + 256] = b1 - largest * x11;
    if (threadIdx.x == 0) acc[b * 8 + 0] = largest;
}

// dotwx = <w, x2>, den2 = <x2,x2>, x2 = y/||y||. w is partial [b][7][512].
__global__ void k_fin2(const float* __restrict__ w, const float* __restrict__ y,
                       float* __restrict__ acc) {
    __shared__ float red[4];
    int b = blockIdx.x;
    const float* wp = w + (size_t)b * NSPLIT * CC;
    const float* yp = y + (size_t)b * CC;
    float w0 = 0.f, w1 = 0.f;
    for (int p = 0; p < NSPLIT; p++) {
        w0 += wp[p * CC + threadIdx.x];
        w1 += wp[p * CC + threadIdx.x + 256];
    }
    float y0 = yp[threadIdx.x], y1 = yp[threadIdx.x + 256];
    float ssy = blk_reduce(y0 * y0 + y1 * y1, red);
    float rn = 1.0f / fmaxf(sqrtf(ssy), FEPS);
    float x20 = y0 * rn, x21 = y1 * rn;
    float dotwx = blk_reduce(w0 * x20 + w1 * x21, red);
    float den2 = blk_reduce(x20 * x20 + x21 * x21, red);
    if (threadIdx.x == 0) { acc[b * 8 + 1] = dotwx; acc[b * 8 + 2] = den2; }
}

__global__ void k_out(const float* __restrict__ acc, float* __restrict__ out) {
    int b = threadIdx.x;                   // 64 threads = 1 wave
    float largest = acc[b * 8 + 0];
    float dotwx   = acc[b * 8 + 1];
    float den2    = acc[b * 8 + 2];
    float tmp = (dotwx - largest * den2) / den2;
    float smallest = tmp + largest;
    float r = largest / smallest - 1.0f;
    float pen = r * r;                     // BETA = 1
    for (int off = 32; off; off >>= 1) pen += __shfl_down(pen, off, 64);
    if (b == 0) out[0] = pen / (float)BB;
}

extern "C" void kernel_launch(void* const* d_in, const int* in_sizes, int n_in,
                              void* d_out, int out_size, void* d_ws, size_t ws_size,
                              hipStream_t stream) {
    const float* A  = (const float*)d_in[0];
    const float* x0 = (const float*)d_in[1];
    float* out = (float*)d_out;
    float* ws = (float*)d_ws;

    float* acc = ws;                          // 512 floats (64 x 8)
    float* y   = ws + 512;                    // BB*CC = 32768
    float* PA  = y + BB * CC;                 // BB*7*CC = 229376
    float* PB  = PA + BB * NSPLIT * CC;       // 229376
    float* T   = PB + BB * NSPLIT * CC;       // BB*BF4*4 floats = 102.8 MB
    const size_t need = ((size_t)492032 + (size_t)BB * BF4 * 4) * sizeof(float);

    dim3 gS(NSPLIT, BB);
    if (ws_size >= need) {
        k_repack<<<dim3(32, BB), 256, 0, stream>>>(A, T);
        k_step<true><<<gS, 256, 0, stream>>>(T, x0, 1, PA);        // t1
        k_step<true><<<gS, 256, 0, stream>>>(T, PA, NSPLIT, PB);   // t2
        k_step<true><<<gS, 256, 0, stream>>>(T, PB, NSPLIT, PA);   // t3
        k_step<true><<<gS, 256, 0, stream>>>(T, PA, NSPLIT, PB);   // t4
        k_step<true><<<gS, 256, 0, stream>>>(T, PB, NSPLIT, PA);   // t5
        k_mid<<<BB, 256, 0, stream>>>(PB, PA, acc, y);
        k_step<true><<<gS, 256, 0, stream>>>(T, y, 1, PB);         // w
        k_fin2<<<BB, 256, 0, stream>>>(PB, y, acc);
    } else {
        k_step<false><<<gS, 256, 0, stream>>>(A, x0, 1, PA);
        k_step<false><<<gS, 256, 0, stream>>>(A, PA, NSPLIT, PB);
        k_step<false><<<gS, 256, 0, stream>>>(A, PB, NSPLIT, PA);
        k_step<false><<<gS, 256, 0, stream>>>(A, PA, NSPLIT, PB);
        k_step<false><<<gS, 256, 0, stream>>>(A, PB, NSPLIT, PA);
        k_mid<<<BB, 256, 0, stream>>>(PB, PA, acc, y);
        k_step<false><<<gS, 256, 0, stream>>>(A, y, 1, PB);
        k_fin2<<<BB, 256, 0, stream>>>(PB, y, acc);
    }
    k_out<<<1, 64, 0, stream>>>(acc, out);
}

// Round 3
// 274.239 us; speedup vs baseline: 1.3542x; 1.3542x over previous
//
#include <hip/hip_runtime.h>
#include <math.h>

// OFPenalty: power-iteration eigen-penalty on AAT = W W^T per batch, never
// materializing AAT. Round 5: barrier-free register-streaming k_step.
//  - R2 falsified the address-pattern theory (sequential reads: no change).
//    Diagnosis now: global_load_lds + 1-deep pipeline + 3 barriers/chunk is
//    convoy-bound at ~2 TB/s regardless of layout.
//  - Fix: repack A -> T2[b][ch][q][c] (quad-major). k_step waves own one
//    float4-quad each; lanes own rows c = lane+64k. Loads are contiguous
//    per-wave 1KB global_load_dwordx4 into REGISTERS (double-buffered, fully
//    unrolled); u reduced by in-wave shfl_xor butterfly; v kept in registers.
//    NO LDS tile, NO barriers in the chunk loop. One 8KB LDS v-reduce at end.
//  - T2 (103 MB) stays L3-resident across all 6 steps.
// A: (64, 512, 28, 28) fp32 -> W: (64, 512, 784). x0: (64, 512, 1).

#define BB 64
#define CC 512
#define DD 784
#define DCH 16
#define NSPLIT 7
#define NCHPS 7         // chunks per split; NSPLIT*NCHPS = 49 = DD/DCH
#define F4PR 196        // float4 per row of A (784/4)
#define BF4 100352      // float4 per batch matrix (512*784/4)
#define FEPS 1e-12f

__device__ __forceinline__ void gload16(const float4* gp, float4* lp) {
    __builtin_amdgcn_global_load_lds(
        (const __attribute__((address_space(1))) void*)gp,
        (__attribute__((address_space(3))) void*)lp, 16, 0, 0);
}

__device__ __forceinline__ float blk_reduce(float s, float* red) {
    for (int off = 32; off; off >>= 1) s += __shfl_down(s, off, 64);
    int w = threadIdx.x >> 6;
    if ((threadIdx.x & 63) == 0) red[w] = s;
    __syncthreads();
    float t = red[0] + red[1] + red[2] + red[3];
    __syncthreads();                       // allow red[] reuse by caller
    return t;
}

// Repack A[b][c][d] -> T2[b][ch][q][c][dq], ch=d>>4, q=(d>>2)&3, dq=d&3.
// Block = (rowblock of 16 c, b). Stage 16 full rows in LDS (50 KB, linear,
// global_load_lds), then write: each (ch,q) gets 16 c x 16B = 256B contiguous
// global segments.
__global__ __launch_bounds__(256, 3)
void k_repack(const float* __restrict__ A, float* __restrict__ T) {
    __shared__ float4 lds4[16 * F4PR];     // 3136 f4 = 50,176 B
    const int tid = threadIdx.x, lane = tid & 63, w = tid >> 6;
    const int b = blockIdx.y, c0 = blockIdx.x * 16;
    const float4* src4 = (const float4*)A + ((size_t)b * CC + c0) * F4PR;
#pragma unroll
    for (int i = 0; i < 12; i++)
        gload16(src4 + i * 256 + w * 64 + lane, lds4 + i * 256 + w * 64);
    if (w == 0) gload16(src4 + 3072 + lane, lds4 + 3072);
    __syncthreads();                        // drains vmcnt before barrier
    float4* dst4 = (float4*)T + (size_t)b * BF4;
#pragma unroll
    for (int j = 0; j < 13; j++) {
        int idx = j * 256 + tid;
        if (idx < 3136) {
            int chq = idx >> 4, i = idx & 15;     // chq = ch*4+q in 0..195
            dst4[(size_t)chq * CC + c0 + i] = lds4[i * F4PR + chq];
        }
    }
}

// vout[b][s][c] = partial of (AAT_b * normalize(sum_p xin[b][p][:]))_c over
// chunks ch = s*7 .. s*7+6. RP: read quad-major T2; else A directly (slow
// fallback, strided). Wave w owns quad w; lane owns rows c = lane + 64k.
template <bool RP>
__global__ __launch_bounds__(256, 2)
void k_step(const float* __restrict__ M, const float* __restrict__ xin,
            const int nparts, float* __restrict__ vout) {
    __shared__ float xs[CC];
    __shared__ float vws[4][CC];
    __shared__ float red[4];

    const int tid = threadIdx.x;
    const int b = blockIdx.y, s = blockIdx.x;
    const int lane = tid & 63, w = tid >> 6;
    const float4* Mb = (const float4*)M + (size_t)b * BF4;

    // ---- phase A: normalize input (sum nparts partial segments)
    const float* xp = xin + (size_t)b * nparts * CC;
    float xv0 = 0.f, xv1 = 0.f;
    for (int p = 0; p < nparts; p++) {
        xv0 += xp[p * CC + tid];
        xv1 += xp[p * CC + tid + 256];
    }
    float ss = blk_reduce(xv0 * xv0 + xv1 * xv1, red);
    float rn = 1.0f / fmaxf(sqrtf(ss), FEPS);
    xs[tid] = xv0 * rn;
    xs[tid + 256] = xv1 * rn;
    __syncthreads();

    float xk[8];
#pragma unroll
    for (int k = 0; k < 8; k++) xk[k] = xs[lane + 64 * k];

    const int ch0 = s * NCHPS;
    float4 a[2][8];
    float vk[8] = {0.f, 0.f, 0.f, 0.f, 0.f, 0.f, 0.f, 0.f};

    auto load = [&](int ch, float4* dst) {
        if (RP) {
            const float4* g = Mb + (size_t)(ch * 4 + w) * CC + lane;
#pragma unroll
            for (int k = 0; k < 8; k++) dst[k] = g[64 * k];
        } else {
            const float4* g = Mb + (size_t)lane * F4PR + ch * 4 + w;
#pragma unroll
            for (int k = 0; k < 8; k++) dst[k] = g[(size_t)64 * k * F4PR];
        }
    };

    load(ch0, a[0]);
#pragma unroll
    for (int j = 0; j < NCHPS; j++) {
        const int cb = j & 1;                      // static after full unroll
        if (j + 1 < NCHPS) load(ch0 + j + 1, a[cb ^ 1]);

        // u-phase: u4[dq] = sum_c A[c][ch*16+w*4+dq] * xhat[c]
        float4 ua = make_float4(0.f, 0.f, 0.f, 0.f);
#pragma unroll
        for (int k = 0; k < 8; k++) {
            ua.x += a[cb][k].x * xk[k]; ua.y += a[cb][k].y * xk[k];
            ua.z += a[cb][k].z * xk[k]; ua.w += a[cb][k].w * xk[k];
        }
#pragma unroll
        for (int off = 1; off < 64; off <<= 1) {
            ua.x += __shfl_xor(ua.x, off, 64);
            ua.y += __shfl_xor(ua.y, off, 64);
            ua.z += __shfl_xor(ua.z, off, 64);
            ua.w += __shfl_xor(ua.w, off, 64);
        }

        // v-phase: vk[k] += A[c][quad] . u4, accumulated across chunks
#pragma unroll
        for (int k = 0; k < 8; k++)
            vk[k] += a[cb][k].x * ua.x + a[cb][k].y * ua.y +
                     a[cb][k].z * ua.z + a[cb][k].w * ua.w;
    }

    // ---- cross-wave v reduction (quads 0..3 live on waves 0..3)
#pragma unroll
    for (int k = 0; k < 8; k++) vws[w][lane + 64 * k] = vk[k];
    __syncthreads();
    float* vp = vout + ((size_t)b * NSPLIT + s) * CC;
    vp[tid]       = vws[0][tid] + vws[1][tid] + vws[2][tid] + vws[3][tid];
    vp[tid + 256] = vws[0][tid + 256] + vws[1][tid + 256] +
                    vws[2][tid + 256] + vws[3][tid + 256];
}

// largest_b = <t5, x1>/<x1,x1>, x1 = t4/||t4||;  y = t5 - largest*x1
// t4, t5 are 7-way partial buffers [b][7][512].
__global__ void k_mid(const float* __restrict__ t4, const float* __restrict__ t5,
                      float* __restrict__ acc, float* __restrict__ y) {
    __shared__ float red[4];
    int b = blockIdx.x;
    const float* p4 = t4 + (size_t)b * NSPLIT * CC;
    const float* p5 = t5 + (size_t)b * NSPLIT * CC;
    float a0 = 0.f, a1 = 0.f, b0 = 0.f, b1 = 0.f;
    for (int p = 0; p < NSPLIT; p++) {
        a0 += p4[p * CC + threadIdx.x]; a1 += p4[p * CC + threadIdx.x + 256];
        b0 += p5[p * CC + threadIdx.x]; b1 += p5[p * CC + threadIdx.x + 256];
    }
    float ss4 = blk_reduce(a0 * a0 + a1 * a1, red);
    float rn = 1.0f / fmaxf(sqrtf(ss4), FEPS);
    float x10 = a0 * rn, x11 = a1 * rn;
    float num = blk_reduce(b0 * x10 + b1 * x11, red);
    float den = blk_reduce(x10 * x10 + x11 * x11, red);
    float largest = num / den;
    float* yp = y + (size_t)b * CC;
    yp[threadIdx.x] = b0 - largest * x10;
    yp[threadIdx.x + 256] = b1 - largest * x11;
    if (threadIdx.x == 0) acc[b * 8 + 0] = largest;
}

// dotwx = <w, x2>, den2 = <x2,x2>, x2 = y/||y||. w is partial [b][7][512].
__global__ void k_fin2(const float* __restrict__ w, const float* __restrict__ y,
                       float* __restrict__ acc) {
    __shared__ float red[4];
    int b = blockIdx.x;
    const float* wp = w + (size_t)b * NSPLIT * CC;
    const float* yp = y + (size_t)b * CC;
    float w0 = 0.f, w1 = 0.f;
    for (int p = 0; p < NSPLIT; p++) {
        w0 += wp[p * CC + threadIdx.x];
        w1 += wp[p * CC + threadIdx.x + 256];
    }
    float y0 = yp[threadIdx.x], y1 = yp[threadIdx.x + 256];
    float ssy = blk_reduce(y0 * y0 + y1 * y1, red);
    float rn = 1.0f / fmaxf(sqrtf(ssy), FEPS);
    float x20 = y0 * rn, x21 = y1 * rn;
    float dotwx = blk_reduce(w0 * x20 + w1 * x21, red);
    float den2 = blk_reduce(x20 * x20 + x21 * x21, red);
    if (threadIdx.x == 0) { acc[b * 8 + 1] = dotwx; acc[b * 8 + 2] = den2; }
}

__global__ void k_out(const float* __restrict__ acc, float* __restrict__ out) {
    int b = threadIdx.x;                   // 64 threads = 1 wave
    float largest = acc[b * 8 + 0];
    float dotwx   = acc[b * 8 + 1];
    float den2    = acc[b * 8 + 2];
    float tmp = (dotwx - largest * den2) / den2;
    float smallest = tmp + largest;
    float r = largest / smallest - 1.0f;
    float pen = r * r;                     // BETA = 1
    for (int off = 32; off; off >>= 1) pen += __shfl_down(pen, off, 64);
    if (b == 0) out[0] = pen / (float)BB;
}

extern "C" void kernel_launch(void* const* d_in, const int* in_sizes, int n_in,
                              void* d_out, int out_size, void* d_ws, size_t ws_size,
                              hipStream_t stream) {
    const float* A  = (const float*)d_in[0];
    const float* x0 = (const float*)d_in[1];
    float* out = (float*)d_out;
    float* ws = (float*)d_ws;

    float* acc = ws;                          // 512 floats (64 x 8)
    float* y   = ws + 512;                    // BB*CC = 32768
    float* PA  = y + BB * CC;                 // BB*7*CC = 229376
    float* PB  = PA + BB * NSPLIT * CC;       // 229376
    float* T   = PB + BB * NSPLIT * CC;       // BB*BF4*4 floats = 102.8 MB
    const size_t need = ((size_t)492032 + (size_t)BB * BF4 * 4) * sizeof(float);

    dim3 gS(NSPLIT, BB);
    if (ws_size >= need) {
        k_repack<<<dim3(32, BB), 256, 0, stream>>>(A, T);
        k_step<true><<<gS, 256, 0, stream>>>(T, x0, 1, PA);        // t1
        k_step<true><<<gS, 256, 0, stream>>>(T, PA, NSPLIT, PB);   // t2
        k_step<true><<<gS, 256, 0, stream>>>(T, PB, NSPLIT, PA);   // t3
        k_step<true><<<gS, 256, 0, stream>>>(T, PA, NSPLIT, PB);   // t4
        k_step<true><<<gS, 256, 0, stream>>>(T, PB, NSPLIT, PA);   // t5
        k_mid<<<BB, 256, 0, stream>>>(PB, PA, acc, y);
        k_step<true><<<gS, 256, 0, stream>>>(T, y, 1, PB);         // w
        k_fin2<<<BB, 256, 0, stream>>>(PB, y, acc);
    } else {
        k_step<false><<<gS, 256, 0, stream>>>(A, x0, 1, PA);
        k_step<false><<<gS, 256, 0, stream>>>(A, PA, NSPLIT, PB);
        k_step<false><<<gS, 256, 0, stream>>>(A, PB, NSPLIT, PA);
        k_step<false><<<gS, 256, 0, stream>>>(A, PA, NSPLIT, PB);
        k_step<false><<<gS, 256, 0, stream>>>(A, PB, NSPLIT, PA);
        k_mid<<<BB, 256, 0, stream>>>(PB, PA, acc, y);
        k_step<false><<<gS, 256, 0, stream>>>(A, y, 1, PB);
        k_fin2<<<BB, 256, 0, stream>>>(PB, y, acc);
    }
    k_out<<<1, 64, 0, stream>>>(acc, out);
}